// Round 1
// 656.458 us; speedup vs baseline: 1.2219x; 1.2219x over previous
//
#include <hip/hip_runtime.h>
#include <hip/hip_bf16.h>

typedef __bf16 v8bf __attribute__((ext_vector_type(8)));
typedef float  v4f  __attribute__((ext_vector_type(4)));

constexpr int N_NODES = 50000;
constexpr int N_EDGES = 800000;
constexpr float LN_EPS = 1e-6f;
constexpr int ROW_TILES = N_NODES / 16;   // 3125, exact

// ---------------- int-width probe (robust to int32/int64 device ints) ----------------
__global__ void probe_kernel(const int* __restrict__ edge, int* __restrict__ flag) {
  int t = threadIdx.x;           // 64 lanes
  int nz = 0;
  for (int i = t * 2 + 1; i < 4096; i += 128) nz |= (edge[i] != 0);
  unsigned long long m = __ballot(nz);
  if (t == 0) flag[0] = (m == 0ull) ? 1 : 0;
}

__device__ __forceinline__ int ld_idx(const void* base, int i, int is64) {
  int v;
  if (is64) v = (int)((const long long*)base)[(long long)i];
  else      v = ((const int*)base)[i];
  if ((unsigned)v >= (unsigned)N_NODES) v = 0;   // defensive clamp
  return v;
}

// ---------------- graph preprocessing ----------------

__global__ void init_kernel(int* __restrict__ deg, int* __restrict__ gcount) {
  int i = blockIdx.x * 256 + threadIdx.x;
  if (i < N_NODES) deg[i] = 1;              // self-loop
  if (i == 0) gcount[0] = 0;
}

__global__ void count_kernel(const void* __restrict__ edge, const int* __restrict__ flag,
                             int* __restrict__ deg) {
  int e = blockIdx.x * 256 + threadIdx.x;
  if (e < N_EDGES) atomicAdd(&deg[ld_idx(edge, N_EDGES + e, flag[0])], 1);
}

// Per-block LDS scan + atomic block-base. CSR ranges need only be disjoint,
// not monotone in node id, since agg derives [start, start+deg-1) per node.
__global__ __launch_bounds__(256) void block_offsets_kernel(
    const int* __restrict__ deg, int* __restrict__ gcount,
    int* __restrict__ rowstart, int* __restrict__ cursor, float* __restrict__ dinv) {
  __shared__ int ps[256];
  __shared__ int base_s;
  int tid = threadIdx.x;
  int node = blockIdx.x * 256 + tid;
  int d = (node < N_NODES) ? deg[node] : 1;
  int cnt = d - 1;                           // real in-edges for this node
  ps[tid] = cnt;
  __syncthreads();
#pragma unroll
  for (int off = 1; off < 256; off <<= 1) {
    int v = (tid >= off) ? ps[tid - off] : 0;
    __syncthreads();
    ps[tid] += v;
    __syncthreads();
  }
  if (tid == 255) base_s = atomicAdd(gcount, ps[255]);
  __syncthreads();
  int start = base_s + ps[tid] - cnt;        // exclusive within block + block base
  if (node < N_NODES) {
    rowstart[node] = start;
    cursor[node]   = start;
    dinv[node]     = rsqrtf((float)max(d, 1));
  }
}

__global__ void scatter_kernel(const void* __restrict__ edge, const int* __restrict__ flag,
                               int* __restrict__ cursor, int* __restrict__ csr_src) {
  int e = blockIdx.x * 256 + threadIdx.x;
  if (e >= N_EDGES) return;
  int f = flag[0];
  int s = ld_idx(edge, e, f);
  int d = ld_idx(edge, N_EDGES + e, f);
  int pos = atomicAdd(&cursor[d], 1);
  if ((unsigned)pos < (unsigned)N_EDGES) csr_src[pos] = s;
}

// ---------------- weight packing (fp32 -> bf16 MFMA B-fragment layout) ----------------
// Wp[((kc*16 + ct)*64 + lane)*8 + j] = W[kc*32 + (lane>>4)*8 + j][ct*16 + (lane&15)]
__global__ void pack_w_kernel(const float* __restrict__ W, __bf16* __restrict__ Wp) {
  int tid = blockIdx.x * 256 + threadIdx.x;
  int j    = tid & 7;
  int lane = (tid >> 3) & 63;
  int ct   = (tid >> 9) & 15;
  int kc   = tid >> 13;
  int k    = kc * 32 + ((lane >> 4) << 3) + j;
  int col  = ct * 16 + (lane & 15);
  Wp[tid] = (__bf16)W[k * 256 + col];
}

// ---------------- x pre-scale: xd[i] = bf16(dinv[i] * x[i]), 128 dims ----------------
__global__ __launch_bounds__(256) void prescale_x_kernel(
    const float* __restrict__ x, const float* __restrict__ dinv, __bf16* __restrict__ xd) {
  int t = blockIdx.x * 256 + threadIdx.x;   // 800000 threads exactly
  int node = t >> 4;
  int d0 = (t & 15) * 8;
  float di = dinv[node];
  v4f f0 = *(const v4f*)(x + (size_t)node * 128 + d0);
  v4f f1 = *(const v4f*)(x + (size_t)node * 128 + d0 + 4);
  v8bf o;
#pragma unroll
  for (int j = 0; j < 4; j++) { o[j] = (__bf16)(di * f0[j]); o[4 + j] = (__bf16)(di * f1[j]); }
  *(v8bf*)(xd + (size_t)node * 128 + d0) = o;
}

// ---------------- aggregation: U[i] = bf16( dinv[i] * (sum_{j in N(i)} Yd[j] + Yd[i]) ) ----
// Yd rows are already pre-scaled by dinv[row]. Plain sum — no per-edge weight gather.
// 16 B/lane: D/8 lanes cover a row; 64/(D/8) edges processed per wave iteration.
template <int D>
__global__ __launch_bounds__(256) void agg_kernel(
    const __bf16* __restrict__ Yd, const int* __restrict__ rowstart,
    const int* __restrict__ deg, const int* __restrict__ csr_src,
    const float* __restrict__ dinv, __bf16* __restrict__ U) {
  constexpr int LPR = D / 8;     // lanes per row: 16 (D=128) or 32 (D=256)
  constexpr int EPW = 64 / LPR;  // edges per wave iter: 4 or 2
  int node = blockIdx.x * 4 + (threadIdx.x >> 6);
  int lane = threadIdx.x & 63;
  int sub = lane / LPR;
  int d0 = (lane % LPR) * 8;

  int start = rowstart[node];
  int cnt = deg[node] - 1;
  start = max(0, min(start, N_EDGES));
  cnt = max(0, min(cnt, N_EDGES - start));
  int e = start, end = start + cnt;

  float di = dinv[node];
  v8bf ys = *(const v8bf*)(Yd + (size_t)node * D + d0);  // issue early, used at end

  float a[8];
#pragma unroll
  for (int j = 0; j < 8; j++) a[j] = 0.f;

  // 2x-unrolled pair loop: 2*EPW edges per iteration, 2 row-loads in flight per sub
  for (; e + 2 * EPW <= end; e += 2 * EPW) {
    int s0 = csr_src[e + sub];
    int s1 = csr_src[e + EPW + sub];
    if ((unsigned)s0 >= (unsigned)N_NODES) s0 = 0;
    if ((unsigned)s1 >= (unsigned)N_NODES) s1 = 0;
    v8bf y0 = *(const v8bf*)(Yd + (size_t)s0 * D + d0);
    v8bf y1 = *(const v8bf*)(Yd + (size_t)s1 * D + d0);
#pragma unroll
    for (int j = 0; j < 8; j++) a[j] += (float)y0[j] + (float)y1[j];
  }
  for (; e + EPW <= end; e += EPW) {
    int s0 = csr_src[e + sub];
    if ((unsigned)s0 >= (unsigned)N_NODES) s0 = 0;
    v8bf y0 = *(const v8bf*)(Yd + (size_t)s0 * D + d0);
#pragma unroll
    for (int j = 0; j < 8; j++) a[j] += (float)y0[j];
  }
  int rem = end - e;
  if (sub < rem) {
    int s0 = csr_src[e + sub];
    if ((unsigned)s0 >= (unsigned)N_NODES) s0 = 0;
    v8bf y0 = *(const v8bf*)(Yd + (size_t)s0 * D + d0);
#pragma unroll
    for (int j = 0; j < 8; j++) a[j] += (float)y0[j];
  }

  // combine edge-slot partials across the wave
#pragma unroll
  for (int off = LPR; off < 64; off <<= 1)
#pragma unroll
    for (int j = 0; j < 8; j++) a[j] += __shfl_xor(a[j], off);

  if (sub == 0) {
    v8bf u;
#pragma unroll
    for (int j = 0; j < 8; j++) u[j] = (__bf16)(di * (a[j] + (float)ys[j]));
    *(v8bf*)(U + (size_t)node * D + d0) = u;
  }
}

// ---------------- MFMA GEMM (A bf16) + fused epilogues ----------------
// mid: Hd[row] = bf16( dinv[row] * (z + relu(z)) ), z = A@W + b
template <int K>
__global__ __launch_bounds__(256, 2) void gemm_mid_kernel(
    const __bf16* __restrict__ A, const __bf16* __restrict__ Wp,
    const float* __restrict__ bias, const float* __restrict__ dinv,
    __bf16* __restrict__ Hd) {
  constexpr int KC = K / 32;
  int lane = threadIdx.x & 63;
  int wave = threadIdx.x >> 6;

  v8bf bfrag[KC][4];
#pragma unroll
  for (int kc = 0; kc < KC; kc++)
#pragma unroll
    for (int c4 = 0; c4 < 4; c4++)
      bfrag[kc][c4] = *(const v8bf*)(Wp + ((size_t)((kc * 16 + wave * 4 + c4) * 64 + lane)) * 8);

  int arow = lane & 15;
  int akq = (lane >> 4) * 8;
  int ccol = wave * 64 + (lane & 15);
  float bcol[4];
#pragma unroll
  for (int c4 = 0; c4 < 4; c4++) bcol[c4] = bias[ccol + c4 * 16];

  for (int t = blockIdx.x; t < ROW_TILES; t += gridDim.x) {
    int row0 = t * 16;
    const __bf16* Ap = A + (size_t)(row0 + arow) * K + akq;
    v8bf af[KC];
#pragma unroll
    for (int kc = 0; kc < KC; kc++) af[kc] = *(const v8bf*)(Ap + kc * 32);

    v4f acc[4];
#pragma unroll
    for (int c4 = 0; c4 < 4; c4++) acc[c4] = (v4f){0.f, 0.f, 0.f, 0.f};
#pragma unroll
    for (int kc = 0; kc < KC; kc++)
#pragma unroll
      for (int c4 = 0; c4 < 4; c4++)
        acc[c4] = __builtin_amdgcn_mfma_f32_16x16x32_bf16(af[kc], bfrag[kc][c4], acc[c4], 0, 0, 0);

    // C/D layout: col = lane&15, row = (lane>>4)*4 + reg  [verified m89]
    int crow = row0 + ((lane >> 4) << 2);
    float dv[4];
#pragma unroll
    for (int r = 0; r < 4; r++) dv[r] = dinv[crow + r];
#pragma unroll
    for (int c4 = 0; c4 < 4; c4++)
#pragma unroll
      for (int r = 0; r < 4; r++) {
        float z = acc[c4][r] + bcol[c4];
        float h = z + fmaxf(z, 0.f);
        Hd[(size_t)(crow + r) * 256 + ccol + c4 * 16] = (__bf16)(dv[r] * h);
      }
  }
}

// final: h = z + relu(z); LayerNorm over 256 dims; write f32
__global__ __launch_bounds__(256, 2) void gemm_final_kernel(
    const __bf16* __restrict__ A, const __bf16* __restrict__ Wp,
    const float* __restrict__ bias, const float* __restrict__ lnw,
    const float* __restrict__ lnb, float* __restrict__ out) {
  constexpr int KC = 8;   // K = 256
  __shared__ float ls1[4][16];
  __shared__ float ls2[4][16];
  int lane = threadIdx.x & 63;
  int wave = threadIdx.x >> 6;

  v8bf bfrag[KC][4];
#pragma unroll
  for (int kc = 0; kc < KC; kc++)
#pragma unroll
    for (int c4 = 0; c4 < 4; c4++)
      bfrag[kc][c4] = *(const v8bf*)(Wp + ((size_t)((kc * 16 + wave * 4 + c4) * 64 + lane)) * 8);

  int arow = lane & 15;
  int akq = (lane >> 4) * 8;
  int g = lane >> 4;
  int ccol = wave * 64 + (lane & 15);
  float bcol[4], wcol[4], lbcol[4];
#pragma unroll
  for (int c4 = 0; c4 < 4; c4++) {
    int col = ccol + c4 * 16;
    bcol[c4] = bias[col];
    wcol[c4] = lnw[col];
    lbcol[c4] = lnb[col];
  }

  for (int t = blockIdx.x; t < ROW_TILES; t += gridDim.x) {
    int row0 = t * 16;
    const __bf16* Ap = A + (size_t)(row0 + arow) * 256 + akq;
    v8bf af[KC];
#pragma unroll
    for (int kc = 0; kc < KC; kc++) af[kc] = *(const v8bf*)(Ap + kc * 32);

    v4f acc[4];
#pragma unroll
    for (int c4 = 0; c4 < 4; c4++) acc[c4] = (v4f){0.f, 0.f, 0.f, 0.f};
#pragma unroll
    for (int kc = 0; kc < KC; kc++)
#pragma unroll
      for (int c4 = 0; c4 < 4; c4++)
        acc[c4] = __builtin_amdgcn_mfma_f32_16x16x32_bf16(af[kc], bfrag[kc][c4], acc[c4], 0, 0, 0);

    float h[4][4];
#pragma unroll
    for (int c4 = 0; c4 < 4; c4++)
#pragma unroll
      for (int r = 0; r < 4; r++) {
        float z = acc[c4][r] + bcol[c4];
        h[c4][r] = z + fmaxf(z, 0.f);
      }

    // per-row partials over this lane's 4 cols
    float s1[4], s2[4];
#pragma unroll
    for (int r = 0; r < 4; r++) {
      s1[r] = 0.f; s2[r] = 0.f;
#pragma unroll
      for (int c4 = 0; c4 < 4; c4++) { s1[r] += h[c4][r]; s2[r] += h[c4][r] * h[c4][r]; }
    }
    // reduce across 16 lanes of same row-group (xor of bits 0..3 keeps lane>>4)
#pragma unroll
    for (int off = 1; off < 16; off <<= 1)
#pragma unroll
      for (int r = 0; r < 4; r++) {
        s1[r] += __shfl_xor(s1[r], off);
        s2[r] += __shfl_xor(s2[r], off);
      }
    if ((lane & 15) == 0) {
#pragma unroll
      for (int r = 0; r < 4; r++) { ls1[wave][g * 4 + r] = s1[r]; ls2[wave][g * 4 + r] = s2[r]; }
    }
    __syncthreads();
#pragma unroll
    for (int r = 0; r < 4; r++) {
      int row = g * 4 + r;
      float t1 = ls1[0][row] + ls1[1][row] + ls1[2][row] + ls1[3][row];
      float t2 = ls2[0][row] + ls2[1][row] + ls2[2][row] + ls2[3][row];
      float mean = t1 * (1.0f / 256.0f);
      float var = t2 * (1.0f / 256.0f) - mean * mean;
      float rstd = rsqrtf(fmaxf(var, 0.f) + LN_EPS);
#pragma unroll
      for (int c4 = 0; c4 < 4; c4++)
        out[(size_t)(row0 + row) * 256 + ccol + c4 * 16] =
            (h[c4][r] - mean) * rstd * wcol[c4] + lbcol[c4];
    }
    __syncthreads();   // protect LDS reuse on next tile
  }
}

__global__ void batchs_kernel(const void* __restrict__ batch, const int* __restrict__ flag,
                              float* __restrict__ ob) {
  int i = blockIdx.x * 256 + threadIdx.x;
  if (i >= N_NODES) return;
  int f = flag[0];
  int v;
  if (f) v = (int)((const long long*)batch)[i];
  else   v = ((const int*)batch)[i];
  float b = (float)v;
  ob[i] = b;
  ob[N_NODES + i] = b;
}

// ---------------- launch ----------------
// Reordered pipeline using S(XW) = (SX)W:
//   xd = dinv .* x (bf16)                              [shared]
//   U0 = S-agg(xd)  (128-dim, bf16)                    [shared across channels]
//   per c: Hd1 = dinv .* phi(U0@W0 + b0)   (GEMM epilogue, bf16, out-region scratch)
//   per c: U = S-agg(Hd1); Hd2 = dinv .* phi(U@W1+b1); U = S-agg(Hd2);
//          out = LN(phi(U@W2 + b2))  (fused in GEMM)

extern "C" void kernel_launch(void* const* d_in, const int* in_sizes, int n_in,
                              void* d_out, int out_size, void* d_ws, size_t ws_size,
                              hipStream_t stream) {
  const float* x    = (const float*)d_in[0];
  const void*  edge = d_in[1];
  const void*  batch= d_in[2];
  const float* W0   = (const float*)d_in[3];
  const float* b0   = (const float*)d_in[4];
  const float* W1   = (const float*)d_in[5];
  const float* b1   = (const float*)d_in[6];
  const float* W2   = (const float*)d_in[7];
  const float* b2   = (const float*)d_in[8];
  const float* lnw  = (const float*)d_in[9];
  const float* lnb  = (const float*)d_in[10];

  // Output layout (verified R6): chunk0 = out [2,50000,256] f32, chunk1 = batchs f32.
  float* out_x = (float*)d_out;
  float* out_b = (float*)d_out + (size_t)2 * N_NODES * 256;

  // workspace layout — ~29.9 MB
  char* p = (char*)d_ws;
  __bf16* Ubuf  = (__bf16*)p;  p += (size_t)N_NODES * 256 * 2;     // 25,600,000
  __bf16* xd    = Ubuf;                          // [N,128] bf16 (first half)
  __bf16* U0    = Ubuf + (size_t)N_NODES * 128;  // [N,128] bf16 (second half)
  __bf16* U256  = Ubuf;                          // [N,256] bf16 (aliases xd+U0, used later)
  int* csr_src  = (int*)p;     p += (size_t)N_EDGES * 4;           //  3,200,000
  int* deg      = (int*)p;     p += (size_t)N_NODES * 4;
  int* cursor   = (int*)p;     p += (size_t)N_NODES * 4;
  int* rowstart = (int*)p;     p += (size_t)N_NODES * 4;
  float* dinv   = (float*)p;   p += (size_t)N_NODES * 4;
  int* flag     = (int*)p;     p += 16;
  int* gcount   = (int*)p;     p += 16;
  __bf16* Wp    = (__bf16*)p;                                      //    655,360 bytes

  const int EB = (N_EDGES + 255) / 256;   // 3125
  const int NB = (N_NODES + 255) / 256;   // 196

  probe_kernel<<<1, 64, 0, stream>>>((const int*)edge, flag);
  init_kernel<<<NB, 256, 0, stream>>>(deg, gcount);
  count_kernel<<<EB, 256, 0, stream>>>(edge, flag, deg);
  block_offsets_kernel<<<NB, 256, 0, stream>>>(deg, gcount, rowstart, cursor, dinv);
  scatter_kernel<<<EB, 256, 0, stream>>>(edge, flag, cursor, csr_src);

  for (int c = 0; c < 2; c++) {
    pack_w_kernel<<<128, 256, 0, stream>>>(W0 + (size_t)c * 128 * 256, Wp + c * 32768);
    pack_w_kernel<<<256, 256, 0, stream>>>(W1 + (size_t)c * 256 * 256, Wp + 65536 + c * 65536);
    pack_w_kernel<<<256, 256, 0, stream>>>(W2 + (size_t)c * 256 * 256, Wp + 196608 + c * 65536);
  }

  // shared layer-0 aggregation at 128 dims
  prescale_x_kernel<<<3125, 256, 0, stream>>>(x, dinv, xd);
  agg_kernel<128><<<N_NODES / 4, 256, 0, stream>>>(xd, rowstart, deg, csr_src, dinv, U0);

  // layer-0 GEMMs for both channels (bf16 Hd scratch lives in each channel's out region)
  for (int c = 0; c < 2; c++) {
    __bf16* Hd = (__bf16*)(out_x + (size_t)c * N_NODES * 256);
    gemm_mid_kernel<128><<<625, 256, 0, stream>>>(U0, Wp + c * 32768, b0 + c * 256, dinv, Hd);
  }

  for (int c = 0; c < 2; c++) {
    __bf16* Hd = (__bf16*)(out_x + (size_t)c * N_NODES * 256);
    agg_kernel<256><<<N_NODES / 4, 256, 0, stream>>>(Hd, rowstart, deg, csr_src, dinv, U256);
    gemm_mid_kernel<256><<<625, 256, 0, stream>>>(U256, Wp + 65536 + c * 65536, b1 + c * 256,
                                                  dinv, Hd);
    agg_kernel<256><<<N_NODES / 4, 256, 0, stream>>>(Hd, rowstart, deg, csr_src, dinv, U256);
    gemm_final_kernel<<<625, 256, 0, stream>>>(U256, Wp + 196608 + c * 65536, b2 + c * 256,
                                               lnw, lnb, out_x + (size_t)c * N_NODES * 256);
  }

  batchs_kernel<<<NB, 256, 0, stream>>>(batch, flag, out_b);
}

// Round 2
// 627.386 us; speedup vs baseline: 1.2785x; 1.0463x over previous
//
#include <hip/hip_runtime.h>
#include <hip/hip_bf16.h>

typedef __bf16 v8bf __attribute__((ext_vector_type(8)));
typedef float  v4f  __attribute__((ext_vector_type(4)));

constexpr int N_NODES = 50000;
constexpr int N_EDGES = 800000;
constexpr float LN_EPS = 1e-6f;
constexpr int ROW_TILES = N_NODES / 16;   // 3125, exact

// ---------------- int-width probe (robust to int32/int64 device ints) ----------------
__global__ void probe_kernel(const int* __restrict__ edge, int* __restrict__ flag) {
  int t = threadIdx.x;           // 64 lanes
  int nz = 0;
  for (int i = t * 2 + 1; i < 4096; i += 128) nz |= (edge[i] != 0);
  unsigned long long m = __ballot(nz);
  if (t == 0) flag[0] = (m == 0ull) ? 1 : 0;
}

__device__ __forceinline__ int ld_idx(const void* base, int i, int is64) {
  int v;
  if (is64) v = (int)((const long long*)base)[(long long)i];
  else      v = ((const int*)base)[i];
  if ((unsigned)v >= (unsigned)N_NODES) v = 0;   // defensive clamp
  return v;
}

// ---------------- graph preprocessing ----------------

__global__ void init_kernel(int* __restrict__ deg, int* __restrict__ gcount) {
  int i = blockIdx.x * 256 + threadIdx.x;
  if (i < N_NODES) deg[i] = 1;              // self-loop
  if (i == 0) gcount[0] = 0;
}

__global__ void count_kernel(const void* __restrict__ edge, const int* __restrict__ flag,
                             int* __restrict__ deg) {
  int e = blockIdx.x * 256 + threadIdx.x;
  if (e < N_EDGES) atomicAdd(&deg[ld_idx(edge, N_EDGES + e, flag[0])], 1);
}

// Per-block LDS scan + atomic block-base. CSR ranges need only be disjoint,
// not monotone in node id, since agg derives [start, start+deg-1) per node.
__global__ __launch_bounds__(256) void block_offsets_kernel(
    const int* __restrict__ deg, int* __restrict__ gcount,
    int* __restrict__ rowstart, int* __restrict__ cursor, float* __restrict__ dinv) {
  __shared__ int ps[256];
  __shared__ int base_s;
  int tid = threadIdx.x;
  int node = blockIdx.x * 256 + tid;
  int d = (node < N_NODES) ? deg[node] : 1;
  int cnt = d - 1;                           // real in-edges for this node
  ps[tid] = cnt;
  __syncthreads();
#pragma unroll
  for (int off = 1; off < 256; off <<= 1) {
    int v = (tid >= off) ? ps[tid - off] : 0;
    __syncthreads();
    ps[tid] += v;
    __syncthreads();
  }
  if (tid == 255) base_s = atomicAdd(gcount, ps[255]);
  __syncthreads();
  int start = base_s + ps[tid] - cnt;        // exclusive within block + block base
  if (node < N_NODES) {
    rowstart[node] = start;
    cursor[node]   = start;
    dinv[node]     = rsqrtf((float)max(d, 1));
  }
}

__global__ void scatter_kernel(const void* __restrict__ edge, const int* __restrict__ flag,
                               int* __restrict__ cursor, int* __restrict__ csr_src) {
  int e = blockIdx.x * 256 + threadIdx.x;
  if (e >= N_EDGES) return;
  int f = flag[0];
  int s = ld_idx(edge, e, f);
  int d = ld_idx(edge, N_EDGES + e, f);
  int pos = atomicAdd(&cursor[d], 1);
  if ((unsigned)pos < (unsigned)N_EDGES) csr_src[pos] = s;
}

// ---------------- weight packing (fp32 -> bf16 MFMA B-fragment layout) ----------------
// Wp[((kc*16 + ct)*64 + lane)*8 + j] = W[kc*32 + (lane>>4)*8 + j][ct*16 + (lane&15)]
__global__ void pack_w_kernel(const float* __restrict__ W, __bf16* __restrict__ Wp) {
  int tid = blockIdx.x * 256 + threadIdx.x;
  int j    = tid & 7;
  int lane = (tid >> 3) & 63;
  int ct   = (tid >> 9) & 15;
  int kc   = tid >> 13;
  int k    = kc * 32 + ((lane >> 4) << 3) + j;
  int col  = ct * 16 + (lane & 15);
  Wp[tid] = (__bf16)W[k * 256 + col];
}

// ---------------- x pre-scale: xd[i] = bf16(dinv[i] * x[i]), 128 dims ----------------
__global__ __launch_bounds__(256) void prescale_x_kernel(
    const float* __restrict__ x, const float* __restrict__ dinv, __bf16* __restrict__ xd) {
  int t = blockIdx.x * 256 + threadIdx.x;   // 800000 threads exactly
  int node = t >> 4;
  int d0 = (t & 15) * 8;
  float di = dinv[node];
  v4f f0 = *(const v4f*)(x + (size_t)node * 128 + d0);
  v4f f1 = *(const v4f*)(x + (size_t)node * 128 + d0 + 4);
  v8bf o;
#pragma unroll
  for (int j = 0; j < 4; j++) { o[j] = (__bf16)(di * f0[j]); o[4 + j] = (__bf16)(di * f1[j]); }
  *(v8bf*)(xd + (size_t)node * 128 + d0) = o;
}

// ---------------- aggregation: U[i] = bf16( dinv[i] * (sum_{j in N(i)} Yd[j] + Yd[i]) ) ----
// Yd rows are pre-scaled by dinv[row]; plain sum, no per-edge weight gather.
// One WAVE per (node, 128-dim segment): 16 lanes per row-segment -> 4 edge slots,
// 16-edge main loop keeps 4 row-loads + 4 idx-loads in flight per lane (MLP).
template <int D>
__global__ __launch_bounds__(256) void agg_kernel(
    const __bf16* __restrict__ Yd, const int* __restrict__ rowstart,
    const int* __restrict__ deg, const int* __restrict__ csr_src,
    const float* __restrict__ dinv, __bf16* __restrict__ U) {
  constexpr int SEGS = D / 128;  // 1 (D=128) or 2 (D=256)
  int w = blockIdx.x * 4 + (threadIdx.x >> 6);
  int lane = threadIdx.x & 63;
  int node, seg;
  if (SEGS == 2) { node = w >> 1; seg = w & 1; } else { node = w; seg = 0; }
  int sub = lane >> 4;                   // 0..3: edge slot
  int d0 = seg * 128 + (lane & 15) * 8;  // 8 bf16 dims per lane

  int start = rowstart[node];
  int cnt = deg[node] - 1;
  start = max(0, min(start, N_EDGES));
  cnt = max(0, min(cnt, N_EDGES - start));
  int e = start, end = start + cnt;

  float di = dinv[node];
  v8bf ys = *(const v8bf*)(Yd + (unsigned)(node * D + d0));  // self row, issued early

  float a[8];
#pragma unroll
  for (int j = 0; j < 8; j++) a[j] = 0.f;

  // 16-edge main loop: 4 independent idx loads + 4 independent row loads per lane
  for (; e + 16 <= end; e += 16) {
    int s0 = csr_src[e + sub];
    int s1 = csr_src[e + 4 + sub];
    int s2 = csr_src[e + 8 + sub];
    int s3 = csr_src[e + 12 + sub];
    if ((unsigned)s0 >= (unsigned)N_NODES) s0 = 0;
    if ((unsigned)s1 >= (unsigned)N_NODES) s1 = 0;
    if ((unsigned)s2 >= (unsigned)N_NODES) s2 = 0;
    if ((unsigned)s3 >= (unsigned)N_NODES) s3 = 0;
    v8bf y0 = *(const v8bf*)(Yd + (unsigned)(s0 * D + d0));
    v8bf y1 = *(const v8bf*)(Yd + (unsigned)(s1 * D + d0));
    v8bf y2 = *(const v8bf*)(Yd + (unsigned)(s2 * D + d0));
    v8bf y3 = *(const v8bf*)(Yd + (unsigned)(s3 * D + d0));
#pragma unroll
    for (int j = 0; j < 8; j++)
      a[j] += ((float)y0[j] + (float)y1[j]) + ((float)y2[j] + (float)y3[j]);
  }
  if (e + 8 <= end) {
    int s0 = csr_src[e + sub];
    int s1 = csr_src[e + 4 + sub];
    if ((unsigned)s0 >= (unsigned)N_NODES) s0 = 0;
    if ((unsigned)s1 >= (unsigned)N_NODES) s1 = 0;
    v8bf y0 = *(const v8bf*)(Yd + (unsigned)(s0 * D + d0));
    v8bf y1 = *(const v8bf*)(Yd + (unsigned)(s1 * D + d0));
#pragma unroll
    for (int j = 0; j < 8; j++) a[j] += (float)y0[j] + (float)y1[j];
    e += 8;
  }
  if (e + 4 <= end) {
    int s0 = csr_src[e + sub];
    if ((unsigned)s0 >= (unsigned)N_NODES) s0 = 0;
    v8bf y0 = *(const v8bf*)(Yd + (unsigned)(s0 * D + d0));
#pragma unroll
    for (int j = 0; j < 8; j++) a[j] += (float)y0[j];
    e += 4;
  }
  int rem = end - e;
  if (sub < rem) {
    int s0 = csr_src[e + sub];
    if ((unsigned)s0 >= (unsigned)N_NODES) s0 = 0;
    v8bf y0 = *(const v8bf*)(Yd + (unsigned)(s0 * D + d0));
#pragma unroll
    for (int j = 0; j < 8; j++) a[j] += (float)y0[j];
  }

  // combine the 4 edge-slot partials (lanes with same lane&15)
#pragma unroll
  for (int off = 16; off < 64; off <<= 1)
#pragma unroll
    for (int j = 0; j < 8; j++) a[j] += __shfl_xor(a[j], off);

  if (sub == 0) {
    v8bf u;
#pragma unroll
    for (int j = 0; j < 8; j++) u[j] = (__bf16)(di * (a[j] + (float)ys[j]));
    *(v8bf*)(U + (unsigned)(node * D + d0)) = u;
  }
}

// ---------------- MFMA GEMM (A bf16) + fused epilogues ----------------
// mid: Hd[row] = bf16( dinv[row] * (z + relu(z)) ), z = A@W + b
template <int K>
__global__ __launch_bounds__(256, 2) void gemm_mid_kernel(
    const __bf16* __restrict__ A, const __bf16* __restrict__ Wp,
    const float* __restrict__ bias, const float* __restrict__ dinv,
    __bf16* __restrict__ Hd) {
  constexpr int KC = K / 32;
  int lane = threadIdx.x & 63;
  int wave = threadIdx.x >> 6;

  v8bf bfrag[KC][4];
#pragma unroll
  for (int kc = 0; kc < KC; kc++)
#pragma unroll
    for (int c4 = 0; c4 < 4; c4++)
      bfrag[kc][c4] = *(const v8bf*)(Wp + ((size_t)((kc * 16 + wave * 4 + c4) * 64 + lane)) * 8);

  int arow = lane & 15;
  int akq = (lane >> 4) * 8;
  int ccol = wave * 64 + (lane & 15);
  float bcol[4];
#pragma unroll
  for (int c4 = 0; c4 < 4; c4++) bcol[c4] = bias[ccol + c4 * 16];

  for (int t = blockIdx.x; t < ROW_TILES; t += gridDim.x) {
    int row0 = t * 16;
    const __bf16* Ap = A + (size_t)(row0 + arow) * K + akq;
    v8bf af[KC];
#pragma unroll
    for (int kc = 0; kc < KC; kc++) af[kc] = *(const v8bf*)(Ap + kc * 32);

    v4f acc[4];
#pragma unroll
    for (int c4 = 0; c4 < 4; c4++) acc[c4] = (v4f){0.f, 0.f, 0.f, 0.f};
#pragma unroll
    for (int kc = 0; kc < KC; kc++)
#pragma unroll
      for (int c4 = 0; c4 < 4; c4++)
        acc[c4] = __builtin_amdgcn_mfma_f32_16x16x32_bf16(af[kc], bfrag[kc][c4], acc[c4], 0, 0, 0);

    // C/D layout: col = lane&15, row = (lane>>4)*4 + reg  [verified m89]
    int crow = row0 + ((lane >> 4) << 2);
    float dv[4];
#pragma unroll
    for (int r = 0; r < 4; r++) dv[r] = dinv[crow + r];
#pragma unroll
    for (int c4 = 0; c4 < 4; c4++)
#pragma unroll
      for (int r = 0; r < 4; r++) {
        float z = acc[c4][r] + bcol[c4];
        float h = z + fmaxf(z, 0.f);
        Hd[(size_t)(crow + r) * 256 + ccol + c4 * 16] = (__bf16)(dv[r] * h);
      }
  }
}

// final: h = z + relu(z); LayerNorm over 256 dims; write f32
__global__ __launch_bounds__(256, 2) void gemm_final_kernel(
    const __bf16* __restrict__ A, const __bf16* __restrict__ Wp,
    const float* __restrict__ bias, const float* __restrict__ lnw,
    const float* __restrict__ lnb, float* __restrict__ out) {
  constexpr int KC = 8;   // K = 256
  __shared__ float ls1[4][16];
  __shared__ float ls2[4][16];
  int lane = threadIdx.x & 63;
  int wave = threadIdx.x >> 6;

  v8bf bfrag[KC][4];
#pragma unroll
  for (int kc = 0; kc < KC; kc++)
#pragma unroll
    for (int c4 = 0; c4 < 4; c4++)
      bfrag[kc][c4] = *(const v8bf*)(Wp + ((size_t)((kc * 16 + wave * 4 + c4) * 64 + lane)) * 8);

  int arow = lane & 15;
  int akq = (lane >> 4) * 8;
  int g = lane >> 4;
  int ccol = wave * 64 + (lane & 15);
  float bcol[4], wcol[4], lbcol[4];
#pragma unroll
  for (int c4 = 0; c4 < 4; c4++) {
    int col = ccol + c4 * 16;
    bcol[c4] = bias[col];
    wcol[c4] = lnw[col];
    lbcol[c4] = lnb[col];
  }

  for (int t = blockIdx.x; t < ROW_TILES; t += gridDim.x) {
    int row0 = t * 16;
    const __bf16* Ap = A + (size_t)(row0 + arow) * 256 + akq;
    v8bf af[KC];
#pragma unroll
    for (int kc = 0; kc < KC; kc++) af[kc] = *(const v8bf*)(Ap + kc * 32);

    v4f acc[4];
#pragma unroll
    for (int c4 = 0; c4 < 4; c4++) acc[c4] = (v4f){0.f, 0.f, 0.f, 0.f};
#pragma unroll
    for (int kc = 0; kc < KC; kc++)
#pragma unroll
      for (int c4 = 0; c4 < 4; c4++)
        acc[c4] = __builtin_amdgcn_mfma_f32_16x16x32_bf16(af[kc], bfrag[kc][c4], acc[c4], 0, 0, 0);

    float h[4][4];
#pragma unroll
    for (int c4 = 0; c4 < 4; c4++)
#pragma unroll
      for (int r = 0; r < 4; r++) {
        float z = acc[c4][r] + bcol[c4];
        h[c4][r] = z + fmaxf(z, 0.f);
      }

    // per-row partials over this lane's 4 cols
    float s1[4], s2[4];
#pragma unroll
    for (int r = 0; r < 4; r++) {
      s1[r] = 0.f; s2[r] = 0.f;
#pragma unroll
      for (int c4 = 0; c4 < 4; c4++) { s1[r] += h[c4][r]; s2[r] += h[c4][r] * h[c4][r]; }
    }
    // reduce across 16 lanes of same row-group (xor of bits 0..3 keeps lane>>4)
#pragma unroll
    for (int off = 1; off < 16; off <<= 1)
#pragma unroll
      for (int r = 0; r < 4; r++) {
        s1[r] += __shfl_xor(s1[r], off);
        s2[r] += __shfl_xor(s2[r], off);
      }
    if ((lane & 15) == 0) {
#pragma unroll
      for (int r = 0; r < 4; r++) { ls1[wave][g * 4 + r] = s1[r]; ls2[wave][g * 4 + r] = s2[r]; }
    }
    __syncthreads();
#pragma unroll
    for (int r = 0; r < 4; r++) {
      int row = g * 4 + r;
      float t1 = ls1[0][row] + ls1[1][row] + ls1[2][row] + ls1[3][row];
      float t2 = ls2[0][row] + ls2[1][row] + ls2[2][row] + ls2[3][row];
      float mean = t1 * (1.0f / 256.0f);
      float var = t2 * (1.0f / 256.0f) - mean * mean;
      float rstd = rsqrtf(fmaxf(var, 0.f) + LN_EPS);
#pragma unroll
      for (int c4 = 0; c4 < 4; c4++)
        out[(size_t)(row0 + row) * 256 + ccol + c4 * 16] =
            (h[c4][r] - mean) * rstd * wcol[c4] + lbcol[c4];
    }
    __syncthreads();   // protect LDS reuse on next tile
  }
}

__global__ void batchs_kernel(const void* __restrict__ batch, const int* __restrict__ flag,
                              float* __restrict__ ob) {
  int i = blockIdx.x * 256 + threadIdx.x;
  if (i >= N_NODES) return;
  int f = flag[0];
  int v;
  if (f) v = (int)((const long long*)batch)[i];
  else   v = ((const int*)batch)[i];
  float b = (float)v;
  ob[i] = b;
  ob[N_NODES + i] = b;
}

// ---------------- launch ----------------
// Pipeline (S(XW) = (SX)W reorder):
//   xd = dinv .* x (bf16); U0 = S-agg(xd) at 128 dims  [shared across channels]
//   per c: Hd = dinv .* phi(U0@W0+b0); U = S-agg(Hd); Hd = dinv .* phi(U@W1+b1);
//          U = S-agg(Hd); out = LN(phi(U@W2+b2))   (all epilogues fused in GEMMs)

extern "C" void kernel_launch(void* const* d_in, const int* in_sizes, int n_in,
                              void* d_out, int out_size, void* d_ws, size_t ws_size,
                              hipStream_t stream) {
  const float* x    = (const float*)d_in[0];
  const void*  edge = d_in[1];
  const void*  batch= d_in[2];
  const float* W0   = (const float*)d_in[3];
  const float* b0   = (const float*)d_in[4];
  const float* W1   = (const float*)d_in[5];
  const float* b1   = (const float*)d_in[6];
  const float* W2   = (const float*)d_in[7];
  const float* b2   = (const float*)d_in[8];
  const float* lnw  = (const float*)d_in[9];
  const float* lnb  = (const float*)d_in[10];

  // Output layout (verified R6): chunk0 = out [2,50000,256] f32, chunk1 = batchs f32.
  float* out_x = (float*)d_out;
  float* out_b = (float*)d_out + (size_t)2 * N_NODES * 256;

  // workspace layout — ~29.9 MB
  char* p = (char*)d_ws;
  __bf16* Ubuf  = (__bf16*)p;  p += (size_t)N_NODES * 256 * 2;     // 25,600,000
  __bf16* xd    = Ubuf;                          // [N,128] bf16 (first half)
  __bf16* U0    = Ubuf + (size_t)N_NODES * 128;  // [N,128] bf16 (second half)
  __bf16* U256  = Ubuf;                          // [N,256] bf16 (aliases xd+U0, used later)
  int* csr_src  = (int*)p;     p += (size_t)N_EDGES * 4;           //  3,200,000
  int* deg      = (int*)p;     p += (size_t)N_NODES * 4;
  int* cursor   = (int*)p;     p += (size_t)N_NODES * 4;
  int* rowstart = (int*)p;     p += (size_t)N_NODES * 4;
  float* dinv   = (float*)p;   p += (size_t)N_NODES * 4;
  int* flag     = (int*)p;     p += 16;
  int* gcount   = (int*)p;     p += 16;
  __bf16* Wp    = (__bf16*)p;                                      //    655,360 bytes

  const int EB = (N_EDGES + 255) / 256;   // 3125
  const int NB = (N_NODES + 255) / 256;   // 196

  probe_kernel<<<1, 64, 0, stream>>>((const int*)edge, flag);
  init_kernel<<<NB, 256, 0, stream>>>(deg, gcount);
  count_kernel<<<EB, 256, 0, stream>>>(edge, flag, deg);
  block_offsets_kernel<<<NB, 256, 0, stream>>>(deg, gcount, rowstart, cursor, dinv);
  scatter_kernel<<<EB, 256, 0, stream>>>(edge, flag, cursor, csr_src);

  for (int c = 0; c < 2; c++) {
    pack_w_kernel<<<128, 256, 0, stream>>>(W0 + (size_t)c * 128 * 256, Wp + c * 32768);
    pack_w_kernel<<<256, 256, 0, stream>>>(W1 + (size_t)c * 256 * 256, Wp + 65536 + c * 65536);
    pack_w_kernel<<<256, 256, 0, stream>>>(W2 + (size_t)c * 256 * 256, Wp + 196608 + c * 65536);
  }

  // shared layer-0 aggregation at 128 dims (1 wave per node)
  prescale_x_kernel<<<3125, 256, 0, stream>>>(x, dinv, xd);
  agg_kernel<128><<<N_NODES / 4, 256, 0, stream>>>(xd, rowstart, deg, csr_src, dinv, U0);

  // layer-0 GEMMs for both channels (bf16 Hd scratch lives in each channel's out region)
  for (int c = 0; c < 2; c++) {
    __bf16* Hd = (__bf16*)(out_x + (size_t)c * N_NODES * 256);
    gemm_mid_kernel<128><<<512, 256, 0, stream>>>(U0, Wp + c * 32768, b0 + c * 256, dinv, Hd);
  }

  for (int c = 0; c < 2; c++) {
    __bf16* Hd = (__bf16*)(out_x + (size_t)c * N_NODES * 256);
    agg_kernel<256><<<N_NODES / 2, 256, 0, stream>>>(Hd, rowstart, deg, csr_src, dinv, U256);
    gemm_mid_kernel<256><<<512, 256, 0, stream>>>(U256, Wp + 65536 + c * 65536, b1 + c * 256,
                                                  dinv, Hd);
    agg_kernel<256><<<N_NODES / 2, 256, 0, stream>>>(Hd, rowstart, deg, csr_src, dinv, U256);
    gemm_final_kernel<<<512, 256, 0, stream>>>(U256, Wp + 196608 + c * 65536, b2 + c * 256,
                                               lnw, lnb, out_x + (size_t)c * N_NODES * 256);
  }

  batchs_kernel<<<NB, 256, 0, stream>>>(batch, flag, out_b);
}

// Round 3
// 613.984 us; speedup vs baseline: 1.3064x; 1.0218x over previous
//
#include <hip/hip_runtime.h>
#include <hip/hip_bf16.h>

typedef __bf16 v8bf __attribute__((ext_vector_type(8)));
typedef float  v4f  __attribute__((ext_vector_type(4)));

constexpr int N_NODES = 50000;
constexpr int N_EDGES = 800000;
constexpr float LN_EPS = 1e-6f;
constexpr int ROW_TILES = N_NODES / 16;   // 3125, exact

// ---------------- int-width probe (robust to int32/int64 device ints) ----------------
__global__ void probe_kernel(const int* __restrict__ edge, int* __restrict__ flag) {
  int t = threadIdx.x;           // 64 lanes
  int nz = 0;
  for (int i = t * 2 + 1; i < 4096; i += 128) nz |= (edge[i] != 0);
  unsigned long long m = __ballot(nz);
  if (t == 0) flag[0] = (m == 0ull) ? 1 : 0;
}

__device__ __forceinline__ int ld_idx(const void* base, int i, int is64) {
  int v;
  if (is64) v = (int)((const long long*)base)[(long long)i];
  else      v = ((const int*)base)[i];
  if ((unsigned)v >= (unsigned)N_NODES) v = 0;   // defensive clamp
  return v;
}

// ---------------- graph preprocessing ----------------

__global__ void init_kernel(int* __restrict__ deg, int* __restrict__ gcount) {
  int i = blockIdx.x * 256 + threadIdx.x;
  if (i < N_NODES) deg[i] = 1;              // self-loop
  if (i == 0) gcount[0] = 0;
}

__global__ void count_kernel(const void* __restrict__ edge, const int* __restrict__ flag,
                             int* __restrict__ deg) {
  int e = blockIdx.x * 256 + threadIdx.x;
  if (e < N_EDGES) atomicAdd(&deg[ld_idx(edge, N_EDGES + e, flag[0])], 1);
}

// Per-block LDS scan + atomic block-base. CSR ranges need only be disjoint,
// not monotone in node id, since agg derives [start, start+deg-1) per node.
__global__ __launch_bounds__(256) void block_offsets_kernel(
    const int* __restrict__ deg, int* __restrict__ gcount,
    int* __restrict__ rowstart, int* __restrict__ cursor, float* __restrict__ dinv) {
  __shared__ int ps[256];
  __shared__ int base_s;
  int tid = threadIdx.x;
  int node = blockIdx.x * 256 + tid;
  int d = (node < N_NODES) ? deg[node] : 1;
  int cnt = d - 1;                           // real in-edges for this node
  ps[tid] = cnt;
  __syncthreads();
#pragma unroll
  for (int off = 1; off < 256; off <<= 1) {
    int v = (tid >= off) ? ps[tid - off] : 0;
    __syncthreads();
    ps[tid] += v;
    __syncthreads();
  }
  if (tid == 255) base_s = atomicAdd(gcount, ps[255]);
  __syncthreads();
  int start = base_s + ps[tid] - cnt;        // exclusive within block + block base
  if (node < N_NODES) {
    rowstart[node] = start;
    cursor[node]   = start;
    dinv[node]     = rsqrtf((float)max(d, 1));
  }
}

__global__ void scatter_kernel(const void* __restrict__ edge, const int* __restrict__ flag,
                               int* __restrict__ cursor, int* __restrict__ csr_src) {
  int e = blockIdx.x * 256 + threadIdx.x;
  if (e >= N_EDGES) return;
  int f = flag[0];
  int s = ld_idx(edge, e, f);
  int d = ld_idx(edge, N_EDGES + e, f);
  int pos = atomicAdd(&cursor[d], 1);
  if ((unsigned)pos < (unsigned)N_EDGES) csr_src[pos] = s;
}

// ---------------- weight packing (fp32 -> bf16 MFMA B-fragment layout) ----------------
// One kernel packs all six weight blocks.
// Wp section layout: W0c0[0,32768) W0c1[32768,65536) W1c0 W1c1 [65536,196608)
//                    W2c0 W2c1 [196608,327680)
// Within a section: Wp[((kc*16 + ct)*64 + lane)*8 + j] = W[kc*32 + (lane>>4)*8 + j][ct*16 + (lane&15)]
__global__ void pack_all_kernel(const float* __restrict__ W0, const float* __restrict__ W1,
                                const float* __restrict__ W2, __bf16* __restrict__ Wp) {
  int tid = blockIdx.x * 256 + threadIdx.x;   // 327680 threads exactly (1280 blocks)
  const float* src; int local;
  if (tid < 65536)       { src = W0 + (size_t)(tid >> 15) * (128 * 256); local = tid & 32767; }
  else if (tid < 196608) { int t2 = tid - 65536;  src = W1 + (size_t)(t2 >> 16) * 65536; local = t2 & 65535; }
  else                   { int t2 = tid - 196608; src = W2 + (size_t)(t2 >> 16) * 65536; local = t2 & 65535; }
  int j    = local & 7;
  int lane = (local >> 3) & 63;
  int ct   = (local >> 9) & 15;
  int kc   = local >> 13;
  int k    = kc * 32 + ((lane >> 4) << 3) + j;
  int col  = ct * 16 + (lane & 15);
  Wp[tid] = (__bf16)src[k * 256 + col];
}

// ---------------- x pre-scale: xd[i] = bf16(dinv[i] * x[i]), 128 dims ----------------
__global__ __launch_bounds__(256) void prescale_x_kernel(
    const float* __restrict__ x, const float* __restrict__ dinv, __bf16* __restrict__ xd) {
  int t = blockIdx.x * 256 + threadIdx.x;   // 800000 threads exactly
  int node = t >> 4;
  int d0 = (t & 15) * 8;
  float di = dinv[node];
  v4f f0 = *(const v4f*)(x + (size_t)node * 128 + d0);
  v4f f1 = *(const v4f*)(x + (size_t)node * 128 + d0 + 4);
  v8bf o;
#pragma unroll
  for (int j = 0; j < 4; j++) { o[j] = (__bf16)(di * f0[j]); o[4 + j] = (__bf16)(di * f1[j]); }
  *(v8bf*)(xd + (size_t)node * 128 + d0) = o;
}

// ---------------- single-table aggregation (used for the shared 128-dim layer-0 pass) ----
// U[i] = bf16( dinv[i] * (sum_{j in N(i)} Yd[j] + Yd[i]) ); Yd rows pre-scaled by dinv.
template <int D>
__global__ __launch_bounds__(256) void agg_kernel(
    const __bf16* __restrict__ Yd, const int* __restrict__ rowstart,
    const int* __restrict__ deg, const int* __restrict__ csr_src,
    const float* __restrict__ dinv, __bf16* __restrict__ U) {
  constexpr int SEGS = D / 128;
  int w = blockIdx.x * 4 + (threadIdx.x >> 6);
  int lane = threadIdx.x & 63;
  int node, seg;
  if (SEGS == 2) { node = w >> 1; seg = w & 1; } else { node = w; seg = 0; }
  int sub = lane >> 4;                   // 0..3: edge slot
  int d0 = seg * 128 + (lane & 15) * 8;  // 8 bf16 dims per lane

  int start = rowstart[node];
  int cnt = deg[node] - 1;
  start = max(0, min(start, N_EDGES));
  cnt = max(0, min(cnt, N_EDGES - start));
  int e = start, end = start + cnt;

  float di = dinv[node];
  v8bf ys = *(const v8bf*)(Yd + (unsigned)(node * D + d0));  // self row, issued early

  float a[8];
#pragma unroll
  for (int j = 0; j < 8; j++) a[j] = 0.f;

  for (; e + 16 <= end; e += 16) {
    int s0 = csr_src[e + sub];
    int s1 = csr_src[e + 4 + sub];
    int s2 = csr_src[e + 8 + sub];
    int s3 = csr_src[e + 12 + sub];
    if ((unsigned)s0 >= (unsigned)N_NODES) s0 = 0;
    if ((unsigned)s1 >= (unsigned)N_NODES) s1 = 0;
    if ((unsigned)s2 >= (unsigned)N_NODES) s2 = 0;
    if ((unsigned)s3 >= (unsigned)N_NODES) s3 = 0;
    v8bf y0 = *(const v8bf*)(Yd + (unsigned)(s0 * D + d0));
    v8bf y1 = *(const v8bf*)(Yd + (unsigned)(s1 * D + d0));
    v8bf y2 = *(const v8bf*)(Yd + (unsigned)(s2 * D + d0));
    v8bf y3 = *(const v8bf*)(Yd + (unsigned)(s3 * D + d0));
#pragma unroll
    for (int j = 0; j < 8; j++)
      a[j] += ((float)y0[j] + (float)y1[j]) + ((float)y2[j] + (float)y3[j]);
  }
  if (e + 8 <= end) {
    int s0 = csr_src[e + sub];
    int s1 = csr_src[e + 4 + sub];
    if ((unsigned)s0 >= (unsigned)N_NODES) s0 = 0;
    if ((unsigned)s1 >= (unsigned)N_NODES) s1 = 0;
    v8bf y0 = *(const v8bf*)(Yd + (unsigned)(s0 * D + d0));
    v8bf y1 = *(const v8bf*)(Yd + (unsigned)(s1 * D + d0));
#pragma unroll
    for (int j = 0; j < 8; j++) a[j] += (float)y0[j] + (float)y1[j];
    e += 8;
  }
  if (e + 4 <= end) {
    int s0 = csr_src[e + sub];
    if ((unsigned)s0 >= (unsigned)N_NODES) s0 = 0;
    v8bf y0 = *(const v8bf*)(Yd + (unsigned)(s0 * D + d0));
#pragma unroll
    for (int j = 0; j < 8; j++) a[j] += (float)y0[j];
    e += 4;
  }
  int rem = end - e;
  if (sub < rem) {
    int s0 = csr_src[e + sub];
    if ((unsigned)s0 >= (unsigned)N_NODES) s0 = 0;
    v8bf y0 = *(const v8bf*)(Yd + (unsigned)(s0 * D + d0));
#pragma unroll
    for (int j = 0; j < 8; j++) a[j] += (float)y0[j];
  }

#pragma unroll
  for (int off = 16; off < 64; off <<= 1)
#pragma unroll
    for (int j = 0; j < 8; j++) a[j] += __shfl_xor(a[j], off);

  if (sub == 0) {
    v8bf u;
#pragma unroll
    for (int j = 0; j < 8; j++) u[j] = (__bf16)(di * (a[j] + (float)ys[j]));
    *(v8bf*)(U + (unsigned)(node * D + d0)) = u;
  }
}

// ---------------- DUAL-channel aggregation at 256 dims ----------------
// Both channels share the edge list: load each csr index once, gather A0[s] and A1[s].
// One wave per (node, 128-dim segment); 4 edge slots; 4 row-loads + 2 idx-loads in flight.
__global__ __launch_bounds__(256) void agg_dual_kernel(
    const __bf16* __restrict__ A0, const __bf16* __restrict__ A1,
    const int* __restrict__ rowstart, const int* __restrict__ deg,
    const int* __restrict__ csr_src, const float* __restrict__ dinv,
    __bf16* __restrict__ U0, __bf16* __restrict__ U1) {
  int w = blockIdx.x * 4 + (threadIdx.x >> 6);
  int lane = threadIdx.x & 63;
  int node = w >> 1, seg = w & 1;
  int sub = lane >> 4;
  int d0 = seg * 128 + (lane & 15) * 8;

  int start = rowstart[node];
  int cnt = deg[node] - 1;
  start = max(0, min(start, N_EDGES));
  cnt = max(0, min(cnt, N_EDGES - start));
  int e = start, end = start + cnt;

  float di = dinv[node];
  v8bf ys0 = *(const v8bf*)(A0 + (unsigned)(node * 256 + d0));  // self rows, issued early
  v8bf ys1 = *(const v8bf*)(A1 + (unsigned)(node * 256 + d0));

  float a0[8], a1[8];
#pragma unroll
  for (int j = 0; j < 8; j++) { a0[j] = 0.f; a1[j] = 0.f; }

  // 8-edge main loop: 2 idx loads + 4 independent 16B row loads per lane
  for (; e + 8 <= end; e += 8) {
    int s0 = csr_src[e + sub];
    int s1 = csr_src[e + 4 + sub];
    if ((unsigned)s0 >= (unsigned)N_NODES) s0 = 0;
    if ((unsigned)s1 >= (unsigned)N_NODES) s1 = 0;
    v8bf x00 = *(const v8bf*)(A0 + (unsigned)(s0 * 256 + d0));
    v8bf x10 = *(const v8bf*)(A1 + (unsigned)(s0 * 256 + d0));
    v8bf x01 = *(const v8bf*)(A0 + (unsigned)(s1 * 256 + d0));
    v8bf x11 = *(const v8bf*)(A1 + (unsigned)(s1 * 256 + d0));
#pragma unroll
    for (int j = 0; j < 8; j++) {
      a0[j] += (float)x00[j] + (float)x01[j];
      a1[j] += (float)x10[j] + (float)x11[j];
    }
  }
  if (e + 4 <= end) {
    int s0 = csr_src[e + sub];
    if ((unsigned)s0 >= (unsigned)N_NODES) s0 = 0;
    v8bf x00 = *(const v8bf*)(A0 + (unsigned)(s0 * 256 + d0));
    v8bf x10 = *(const v8bf*)(A1 + (unsigned)(s0 * 256 + d0));
#pragma unroll
    for (int j = 0; j < 8; j++) { a0[j] += (float)x00[j]; a1[j] += (float)x10[j]; }
    e += 4;
  }
  int rem = end - e;
  if (sub < rem) {
    int s0 = csr_src[e + sub];
    if ((unsigned)s0 >= (unsigned)N_NODES) s0 = 0;
    v8bf x00 = *(const v8bf*)(A0 + (unsigned)(s0 * 256 + d0));
    v8bf x10 = *(const v8bf*)(A1 + (unsigned)(s0 * 256 + d0));
#pragma unroll
    for (int j = 0; j < 8; j++) { a0[j] += (float)x00[j]; a1[j] += (float)x10[j]; }
  }

  // combine the 4 edge-slot partials
#pragma unroll
  for (int off = 16; off < 64; off <<= 1)
#pragma unroll
    for (int j = 0; j < 8; j++) {
      a0[j] += __shfl_xor(a0[j], off);
      a1[j] += __shfl_xor(a1[j], off);
    }

  if (sub == 0) {
    v8bf u0, u1;
#pragma unroll
    for (int j = 0; j < 8; j++) {
      u0[j] = (__bf16)(di * (a0[j] + (float)ys0[j]));
      u1[j] = (__bf16)(di * (a1[j] + (float)ys1[j]));
    }
    *(v8bf*)(U0 + (unsigned)(node * 256 + d0)) = u0;
    *(v8bf*)(U1 + (unsigned)(node * 256 + d0)) = u1;
  }
}

// ---------------- MFMA GEMM (A bf16) + fused epilogues ----------------
// mid: Hd[row] = bf16( dinv[row] * (z + relu(z)) ), z = A@W + b
template <int K>
__global__ __launch_bounds__(256, 2) void gemm_mid_kernel(
    const __bf16* __restrict__ A, const __bf16* __restrict__ Wp,
    const float* __restrict__ bias, const float* __restrict__ dinv,
    __bf16* __restrict__ Hd) {
  constexpr int KC = K / 32;
  int lane = threadIdx.x & 63;
  int wave = threadIdx.x >> 6;

  v8bf bfrag[KC][4];
#pragma unroll
  for (int kc = 0; kc < KC; kc++)
#pragma unroll
    for (int c4 = 0; c4 < 4; c4++)
      bfrag[kc][c4] = *(const v8bf*)(Wp + ((size_t)((kc * 16 + wave * 4 + c4) * 64 + lane)) * 8);

  int arow = lane & 15;
  int akq = (lane >> 4) * 8;
  int ccol = wave * 64 + (lane & 15);
  float bcol[4];
#pragma unroll
  for (int c4 = 0; c4 < 4; c4++) bcol[c4] = bias[ccol + c4 * 16];

  for (int t = blockIdx.x; t < ROW_TILES; t += gridDim.x) {
    int row0 = t * 16;
    const __bf16* Ap = A + (size_t)(row0 + arow) * K + akq;
    v8bf af[KC];
#pragma unroll
    for (int kc = 0; kc < KC; kc++) af[kc] = *(const v8bf*)(Ap + kc * 32);

    v4f acc[4];
#pragma unroll
    for (int c4 = 0; c4 < 4; c4++) acc[c4] = (v4f){0.f, 0.f, 0.f, 0.f};
#pragma unroll
    for (int kc = 0; kc < KC; kc++)
#pragma unroll
      for (int c4 = 0; c4 < 4; c4++)
        acc[c4] = __builtin_amdgcn_mfma_f32_16x16x32_bf16(af[kc], bfrag[kc][c4], acc[c4], 0, 0, 0);

    // C/D layout: col = lane&15, row = (lane>>4)*4 + reg  [verified m89]
    int crow = row0 + ((lane >> 4) << 2);
    float dv[4];
#pragma unroll
    for (int r = 0; r < 4; r++) dv[r] = dinv[crow + r];
#pragma unroll
    for (int c4 = 0; c4 < 4; c4++)
#pragma unroll
      for (int r = 0; r < 4; r++) {
        float z = acc[c4][r] + bcol[c4];
        float h = z + fmaxf(z, 0.f);
        Hd[(size_t)(crow + r) * 256 + ccol + c4 * 16] = (__bf16)(dv[r] * h);
      }
  }
}

// final: h = z + relu(z); LayerNorm over 256 dims; write f32
__global__ __launch_bounds__(256, 2) void gemm_final_kernel(
    const __bf16* __restrict__ A, const __bf16* __restrict__ Wp,
    const float* __restrict__ bias, const float* __restrict__ lnw,
    const float* __restrict__ lnb, float* __restrict__ out) {
  constexpr int KC = 8;   // K = 256
  __shared__ float ls1[4][16];
  __shared__ float ls2[4][16];
  int lane = threadIdx.x & 63;
  int wave = threadIdx.x >> 6;

  v8bf bfrag[KC][4];
#pragma unroll
  for (int kc = 0; kc < KC; kc++)
#pragma unroll
    for (int c4 = 0; c4 < 4; c4++)
      bfrag[kc][c4] = *(const v8bf*)(Wp + ((size_t)((kc * 16 + wave * 4 + c4) * 64 + lane)) * 8);

  int arow = lane & 15;
  int akq = (lane >> 4) * 8;
  int g = lane >> 4;
  int ccol = wave * 64 + (lane & 15);
  float bcol[4], wcol[4], lbcol[4];
#pragma unroll
  for (int c4 = 0; c4 < 4; c4++) {
    int col = ccol + c4 * 16;
    bcol[c4] = bias[col];
    wcol[c4] = lnw[col];
    lbcol[c4] = lnb[col];
  }

  for (int t = blockIdx.x; t < ROW_TILES; t += gridDim.x) {
    int row0 = t * 16;
    const __bf16* Ap = A + (size_t)(row0 + arow) * 256 + akq;
    v8bf af[KC];
#pragma unroll
    for (int kc = 0; kc < KC; kc++) af[kc] = *(const v8bf*)(Ap + kc * 32);

    v4f acc[4];
#pragma unroll
    for (int c4 = 0; c4 < 4; c4++) acc[c4] = (v4f){0.f, 0.f, 0.f, 0.f};
#pragma unroll
    for (int kc = 0; kc < KC; kc++)
#pragma unroll
      for (int c4 = 0; c4 < 4; c4++)
        acc[c4] = __builtin_amdgcn_mfma_f32_16x16x32_bf16(af[kc], bfrag[kc][c4], acc[c4], 0, 0, 0);

    float h[4][4];
#pragma unroll
    for (int c4 = 0; c4 < 4; c4++)
#pragma unroll
      for (int r = 0; r < 4; r++) {
        float z = acc[c4][r] + bcol[c4];
        h[c4][r] = z + fmaxf(z, 0.f);
      }

    float s1[4], s2[4];
#pragma unroll
    for (int r = 0; r < 4; r++) {
      s1[r] = 0.f; s2[r] = 0.f;
#pragma unroll
      for (int c4 = 0; c4 < 4; c4++) { s1[r] += h[c4][r]; s2[r] += h[c4][r] * h[c4][r]; }
    }
#pragma unroll
    for (int off = 1; off < 16; off <<= 1)
#pragma unroll
      for (int r = 0; r < 4; r++) {
        s1[r] += __shfl_xor(s1[r], off);
        s2[r] += __shfl_xor(s2[r], off);
      }
    if ((lane & 15) == 0) {
#pragma unroll
      for (int r = 0; r < 4; r++) { ls1[wave][g * 4 + r] = s1[r]; ls2[wave][g * 4 + r] = s2[r]; }
    }
    __syncthreads();
#pragma unroll
    for (int r = 0; r < 4; r++) {
      int row = g * 4 + r;
      float t1 = ls1[0][row] + ls1[1][row] + ls1[2][row] + ls1[3][row];
      float t2 = ls2[0][row] + ls2[1][row] + ls2[2][row] + ls2[3][row];
      float mean = t1 * (1.0f / 256.0f);
      float var = t2 * (1.0f / 256.0f) - mean * mean;
      float rstd = rsqrtf(fmaxf(var, 0.f) + LN_EPS);
#pragma unroll
      for (int c4 = 0; c4 < 4; c4++)
        out[(size_t)(row0 + row) * 256 + ccol + c4 * 16] =
            (h[c4][r] - mean) * rstd * wcol[c4] + lbcol[c4];
    }
    __syncthreads();   // protect LDS reuse on next tile
  }
}

__global__ void batchs_kernel(const void* __restrict__ batch, const int* __restrict__ flag,
                              float* __restrict__ ob) {
  int i = blockIdx.x * 256 + threadIdx.x;
  if (i >= N_NODES) return;
  int f = flag[0];
  int v;
  if (f) v = (int)((const long long*)batch)[i];
  else   v = ((const int*)batch)[i];
  float b = (float)v;
  ob[i] = b;
  ob[N_NODES + i] = b;
}

// ---------------- launch ----------------
// Pipeline (S(XW) = (SX)W reorder, dual-channel aggregation):
//   xd = dinv.*x (bf16); U0 = S-agg(xd) @128              [shared]
//   Hd_c = dinv .* phi(U0@W0c+b0c)  (c=0,1)
//   dual-agg: {Hd0,Hd1} -> {UA0 (ws), UA1 (region1 2nd half)}
//   Hd_c = dinv .* phi(UAc@W1c+b1c)
//   dual-agg: {Hd0,Hd1} -> {UB0 (ws), UB1 (region0 2nd half)}
//   out1 = LN(phi(UB1@W2c1+b2c1))   [c1 FIRST: c0's write clobbers UB1's home]
//   out0 = LN(phi(UB0@W2c0+b2c0))

extern "C" void kernel_launch(void* const* d_in, const int* in_sizes, int n_in,
                              void* d_out, int out_size, void* d_ws, size_t ws_size,
                              hipStream_t stream) {
  const float* x    = (const float*)d_in[0];
  const void*  edge = d_in[1];
  const void*  batch= d_in[2];
  const float* W0   = (const float*)d_in[3];
  const float* b0   = (const float*)d_in[4];
  const float* W1   = (const float*)d_in[5];
  const float* b1   = (const float*)d_in[6];
  const float* W2   = (const float*)d_in[7];
  const float* b2   = (const float*)d_in[8];
  const float* lnw  = (const float*)d_in[9];
  const float* lnb  = (const float*)d_in[10];

  // Output layout (verified R6): chunk0 = out [2,50000,256] f32, chunk1 = batchs f32.
  float* out_x = (float*)d_out;
  float* out_b = (float*)d_out + (size_t)2 * N_NODES * 256;

  // out-region scratch (each channel region = 51.2 MB f32; halves are 25.6 MB):
  //   region c 1st half: Hd_c (bf16 [N,256])
  //   region c 2nd half: U-channel-1 staging (bf16 [N,256])
  __bf16* Hd0   = (__bf16*)out_x;                                   // region0 1st half
  __bf16* Hd1   = (__bf16*)(out_x + (size_t)N_NODES * 256);         // region1 1st half
  __bf16* R0hi  = (__bf16*)(out_x + (size_t)N_NODES * 128);         // region0 2nd half
  __bf16* R1hi  = (__bf16*)(out_x + (size_t)N_NODES * 256 + (size_t)N_NODES * 128); // region1 2nd half

  // workspace layout — ~29.9 MB
  char* p = (char*)d_ws;
  __bf16* Ubuf  = (__bf16*)p;  p += (size_t)N_NODES * 256 * 2;     // 25,600,000
  __bf16* xd    = Ubuf;                          // [N,128] bf16 (first half)
  __bf16* U0    = Ubuf + (size_t)N_NODES * 128;  // [N,128] bf16 (second half)
  int* csr_src  = (int*)p;     p += (size_t)N_EDGES * 4;           //  3,200,000
  int* deg      = (int*)p;     p += (size_t)N_NODES * 4;
  int* cursor   = (int*)p;     p += (size_t)N_NODES * 4;
  int* rowstart = (int*)p;     p += (size_t)N_NODES * 4;
  float* dinv   = (float*)p;   p += (size_t)N_NODES * 4;
  int* flag     = (int*)p;     p += 16;
  int* gcount   = (int*)p;     p += 16;
  __bf16* Wp    = (__bf16*)p;                                      //    655,360 bytes

  const int EB = (N_EDGES + 255) / 256;   // 3125
  const int NB = (N_NODES + 255) / 256;   // 196

  probe_kernel<<<1, 64, 0, stream>>>((const int*)edge, flag);
  init_kernel<<<NB, 256, 0, stream>>>(deg, gcount);
  count_kernel<<<EB, 256, 0, stream>>>(edge, flag, deg);
  block_offsets_kernel<<<NB, 256, 0, stream>>>(deg, gcount, rowstart, cursor, dinv);
  scatter_kernel<<<EB, 256, 0, stream>>>(edge, flag, cursor, csr_src);

  pack_all_kernel<<<1280, 256, 0, stream>>>(W0, W1, W2, Wp);

  // shared layer-0 aggregation at 128 dims
  prescale_x_kernel<<<3125, 256, 0, stream>>>(x, dinv, xd);
  agg_kernel<128><<<N_NODES / 4, 256, 0, stream>>>(xd, rowstart, deg, csr_src, dinv, U0);

  // layer-0 GEMMs (Hd_c bf16 scratch in each region's 1st half)
  gemm_mid_kernel<128><<<512, 256, 0, stream>>>(U0, Wp, b0, dinv, Hd0);
  gemm_mid_kernel<128><<<512, 256, 0, stream>>>(U0, Wp + 32768, b0 + 256, dinv, Hd1);

  // boundary A: dual agg -> UA0 (Ubuf), UA1 (region1 2nd half)
  agg_dual_kernel<<<N_NODES / 2, 256, 0, stream>>>(Hd0, Hd1, rowstart, deg, csr_src, dinv,
                                                   Ubuf, R1hi);
  gemm_mid_kernel<256><<<512, 256, 0, stream>>>(Ubuf, Wp + 65536, b1, dinv, Hd0);
  gemm_mid_kernel<256><<<512, 256, 0, stream>>>(R1hi, Wp + 131072, b1 + 256, dinv, Hd1);

  // boundary B: dual agg -> UB0 (Ubuf), UB1 (region0 2nd half)
  agg_dual_kernel<<<N_NODES / 2, 256, 0, stream>>>(Hd0, Hd1, rowstart, deg, csr_src, dinv,
                                                   Ubuf, R0hi);
  // c1 first: reads region0 2nd half, writes region1; then c0 overwrites region0
  gemm_final_kernel<<<512, 256, 0, stream>>>(R0hi, Wp + 262144, b2 + 256, lnw, lnb,
                                             out_x + (size_t)N_NODES * 256);
  gemm_final_kernel<<<512, 256, 0, stream>>>(Ubuf, Wp + 196608, b2, lnw, lnb, out_x);

  batchs_kernel<<<NB, 256, 0, stream>>>(batch, flag, out_b);
}